// Round 10
// baseline (24.603 us; speedup 1.0000x reference)
//
#include <hip/hip_runtime.h>
#include <hip/hip_bf16.h>
#include <hip/hip_fp16.h>

#define BATCH 16384
#define HIST  50
#define ITEM_ROWS 100001
#define EMB   64

typedef float v2f __attribute__((ext_vector_type(2)));

// DPP row_ror (16-lane row scope) reduction — pure VALU, no LDS pipe.
template<int CTRL>
__device__ __forceinline__ float dpp_mov(float x) {
    return __builtin_bit_cast(float,
        __builtin_amdgcn_update_dpp(0, __builtin_bit_cast(int, x),
                                    CTRL, 0xF, 0xF, true));
}
__device__ __forceinline__ float red16_add(float x) {
    x += dpp_mov<0x128>(x);   // row_ror:8
    x += dpp_mov<0x124>(x);   // row_ror:4
    x += dpp_mov<0x122>(x);   // row_ror:2
    x += dpp_mov<0x121>(x);   // row_ror:1
    return x;
}
__device__ __forceinline__ float dot4(float4 a, float4 b) {
    return a.x*b.x + a.y*b.y + a.z*b.z + a.w*b.w;
}

// ---- kernel 1: fp32 item table -> fp8 e4m3 table in workspace ----
__global__ __launch_bounds__(256) void cvt_fp8_kernel(
    const float4* __restrict__ in4, uint2* __restrict__ out, int n8)
{
    const int i = blockIdx.x * 256 + threadIdx.x;
    if (i >= n8) return;
    const float4 x0 = in4[2 * i];
    const float4 x1 = in4[2 * i + 1];
    int p0 = 0, p1 = 0;
    p0 = __builtin_amdgcn_cvt_pk_fp8_f32(x0.x, x0.y, p0, false);
    p0 = __builtin_amdgcn_cvt_pk_fp8_f32(x0.z, x0.w, p0, true);
    p1 = __builtin_amdgcn_cvt_pk_fp8_f32(x1.x, x1.y, p1, false);
    p1 = __builtin_amdgcn_cvt_pk_fp8_f32(x1.z, x1.w, p1, true);
    out[i] = make_uint2((unsigned)p0, (unsigned)p1);
}

// ---- kernel 2: 2 batch elements per wave, 26 gather lines in flight.
// 4 groups of 16 lanes; group g handles rows 13/13/12/12 of each element.
// x-rows: fp8 (64 B/row = 1 line). y/u rows: original fp32 (coalesced).
// out[b] = sigmoid( sum_l z_l*w_l + u_e.y_e ), z = softmax(w)  [BETA=ALPHA=1]
__global__ __launch_bounds__(256, 3) void RUM_72980084294375_kernel(
    const int* __restrict__ u, const int* __restrict__ X, const int* __restrict__ y,
    const unsigned* __restrict__ item8, const float* __restrict__ item_emb,
    const float* __restrict__ user_emb, float* __restrict__ out)
{
    const int tid    = threadIdx.x;
    const int wave   = tid >> 6;
    const int lane   = tid & 63;
    const int lane16 = lane & 15;
    const int g      = lane >> 4;
    const int wid    = blockIdx.x * 4 + wave;
    const int b0     = __builtin_amdgcn_readfirstlane(2 * wid);
    const int b1     = b0 + 1;

    // issue ALL independent loads up front
    int xi0 = 0, xi1 = 0;
    if (lane < HIST) {
        xi0 = X[b0 * HIST + lane];                      // coalesced 200 B
        xi1 = X[b1 * HIST + lane];
    }

    const float4* item4 = reinterpret_cast<const float4*>(item_emb);
    const float4* user4 = reinterpret_cast<const float4*>(user_emb);
    const int yi0 = y[b0], yi1 = y[b1];                 // wave-uniform scalars
    const int ui0 = u[b0], ui1 = u[b1];
    const float4 y4a = item4[(size_t)yi0 * 16 + lane16];
    const float4 y4b = item4[(size_t)yi1 * 16 + lane16];
    const float4 u4a = user4[(size_t)ui0 * 16 + lane16];
    const float4 u4b = user4[(size_t)ui1 * 16 + lane16];

    const int start = (g < 2) ? g * 13 : 26 + (g - 2) * 12;
    const int count = (g < 2) ? 13 : 12;

    // issue all 26 row-gathers back-to-back (1 x 64 B line per row)
    unsigned q0[13], q1[13];
    #pragma unroll
    for (int k = 0; k < 13; ++k) {
        const int s0 = __shfl(xi0, start + k, 64);
        q0[k] = item8[(size_t)((k < count) ? s0 : 0) * 16 + lane16];
    }
    #pragma unroll
    for (int k = 0; k < 13; ++k) {
        const int s1 = __shfl(xi1, start + k, 64);
        q1[k] = item8[(size_t)((k < count) ? s1 : 0) * 16 + lane16];
    }

    const float uya = red16_add(dot4(u4a, y4a));        // overlaps gathers
    const float uyb = red16_add(dot4(u4b, y4b));

    // decode + dot + 16-lane reduce, element A then element B
    float wva = -1e30f, wvb = -1e30f;
    #pragma unroll
    for (int k = 0; k < 13; ++k) {
        const v2f lo = __builtin_amdgcn_cvt_pk_f32_fp8((int)q0[k], false);
        const v2f hi = __builtin_amdgcn_cvt_pk_f32_fp8((int)q0[k], true);
        const float w = red16_add(lo.x*y4a.x + lo.y*y4a.y + hi.x*y4a.z + hi.y*y4a.w);
        if (k < count && lane16 == k) wva = w;
    }
    #pragma unroll
    for (int k = 0; k < 13; ++k) {
        const v2f lo = __builtin_amdgcn_cvt_pk_f32_fp8((int)q1[k], false);
        const v2f hi = __builtin_amdgcn_cvt_pk_f32_fp8((int)q1[k], true);
        const float w = red16_add(lo.x*y4b.x + lo.y*y4b.y + hi.x*y4b.z + hi.y*y4b.w);
        if (k < count && lane16 == k) wvb = w;
    }

    // softmax-weighted mean of w for both elements
    float ma = wva, mb = wvb;
    #pragma unroll
    for (int d = 1; d < 16; d <<= 1) {
        ma = fmaxf(ma, __shfl_xor(ma, d, 16));
        mb = fmaxf(mb, __shfl_xor(mb, d, 16));
    }
    ma = fmaxf(ma, __shfl_xor(ma, 16, 64));
    ma = fmaxf(ma, __shfl_xor(ma, 32, 64));
    mb = fmaxf(mb, __shfl_xor(mb, 16, 64));
    mb = fmaxf(mb, __shfl_xor(mb, 32, 64));

    const float ea = __expf(wva - ma);                  // pads: exp(-huge)=0
    const float eb = __expf(wvb - mb);
    float sa = red16_add(ea), ta = red16_add(ea * wva);
    float sb = red16_add(eb), tb = red16_add(eb * wvb);
    sa += __shfl_xor(sa, 16, 64);  sa += __shfl_xor(sa, 32, 64);
    ta += __shfl_xor(ta, 16, 64);  ta += __shfl_xor(ta, 32, 64);
    sb += __shfl_xor(sb, 16, 64);  sb += __shfl_xor(sb, 32, 64);
    tb += __shfl_xor(tb, 16, 64);  tb += __shfl_xor(tb, 32, 64);

    if (lane == 0) {
        const float la = ta / sa + uya;
        const float lb = tb / sb + uyb;
        out[b0] = 1.0f / (1.0f + __expf(-la));
        out[b1] = 1.0f / (1.0f + __expf(-lb));
    }
}

// ---- fp32 fallback if ws is too small (R7 structure) ----
__global__ __launch_bounds__(256, 4) void RUM_72980084294375_f32_kernel(
    const int* __restrict__ u, const int* __restrict__ X, const int* __restrict__ y,
    const float* __restrict__ item_emb, const float* __restrict__ user_emb,
    float* __restrict__ out)
{
    __shared__ int sX[4 * HIST];
    const int tid = threadIdx.x;
    const int b0  = blockIdx.x * 4;

    const int wave   = tid >> 6;
    const int lane   = tid & 63;
    const int lane16 = lane & 15;
    const int g      = lane >> 4;
    const int b      = __builtin_amdgcn_readfirstlane(b0 + wave);

    const float4* item4 = reinterpret_cast<const float4*>(item_emb);
    const float4* user4 = reinterpret_cast<const float4*>(user_emb);
    const int yi = y[b];
    const int ui = u[b];
    const float4 y4 = item4[(size_t)yi * 16 + lane16];
    const float4 u4 = user4[(size_t)ui * 16 + lane16];

    if (tid < 4 * HIST) sX[tid] = X[b0 * HIST + tid];
    __syncthreads();

    const float uy = red16_add(dot4(u4, y4));

    const int start = (g < 2) ? g * 13 : 26 + (g - 2) * 12;
    const int count = (g < 2) ? 13 : 12;
    const int* wX = sX + wave * HIST;

    float wv = -1e30f;
    #pragma unroll
    for (int k = 0; k < 13; ++k) {
        const int idx = (k < count) ? wX[start + k] : 0;
        const float4 x4 = item4[(size_t)idx * 16 + lane16];
        float wk = red16_add(dot4(x4, y4));
        if (k < count && lane16 == k) wv = wk;
    }

    float m = wv;
    #pragma unroll
    for (int d = 1; d < 16; d <<= 1) m = fmaxf(m, __shfl_xor(m, d, 16));
    m = fmaxf(m, __shfl_xor(m, 16, 64));
    m = fmaxf(m, __shfl_xor(m, 32, 64));

    const float e = __expf(wv - m);
    float s = red16_add(e);
    float t = red16_add(e * wv);
    s += __shfl_xor(s, 16, 64);  s += __shfl_xor(s, 32, 64);
    t += __shfl_xor(t, 16, 64);  t += __shfl_xor(t, 32, 64);

    if (lane == 0) {
        const float logit = t / s + uy;
        out[b] = 1.0f / (1.0f + __expf(-logit));
    }
}

extern "C" void kernel_launch(void* const* d_in, const int* in_sizes, int n_in,
                              void* d_out, int out_size, void* d_ws, size_t ws_size,
                              hipStream_t stream) {
    const int*   u        = (const int*)d_in[0];
    const int*   X        = (const int*)d_in[1];
    const int*   y        = (const int*)d_in[2];
    const float* item_emb = (const float*)d_in[3];
    const float* user_emb = (const float*)d_in[4];
    float*       out      = (float*)d_out;

    const size_t need = (size_t)ITEM_ROWS * EMB;     // 6.4 MB fp8 table

    if (ws_size >= need) {
        const int n8 = ITEM_ROWS * EMB / 8;          // 800008 (divides exactly)
        cvt_fp8_kernel<<<(n8 + 255) / 256, 256, 0, stream>>>(
            (const float4*)item_emb, (uint2*)d_ws, n8);
        RUM_72980084294375_kernel<<<BATCH / 8, 256, 0, stream>>>(
            u, X, y, (const unsigned*)d_ws, item_emb, user_emb, out);
    } else {
        RUM_72980084294375_f32_kernel<<<BATCH / 4, 256, 0, stream>>>(
            u, X, y, item_emb, user_emb, out);
    }
}

// Round 11
// 24.548 us; speedup vs baseline: 1.0022x; 1.0022x over previous
//
#include <hip/hip_runtime.h>
#include <hip/hip_bf16.h>
#include <hip/hip_fp16.h>

#define BATCH 16384
#define HIST  50
#define ITEM_ROWS 100001
#define EMB   64
// int4 quantization: q = clamp(round(x * 64), -8, 7); dequant folds 1/64 into y.
// Table row = 64 * 4 bits = 32 B -> 3.2 MB total, fits per-XCD 4 MiB L2.

// DPP row_ror (16-lane row scope) reduction — pure VALU, no LDS pipe.
template<int CTRL>
__device__ __forceinline__ float dpp_mov(float x) {
    return __builtin_bit_cast(float,
        __builtin_amdgcn_update_dpp(0, __builtin_bit_cast(int, x),
                                    CTRL, 0xF, 0xF, true));
}
__device__ __forceinline__ float red16_add(float x) {
    x += dpp_mov<0x128>(x);   // row_ror:8
    x += dpp_mov<0x124>(x);   // row_ror:4
    x += dpp_mov<0x122>(x);   // row_ror:2
    x += dpp_mov<0x121>(x);   // row_ror:1
    return x;
}
__device__ __forceinline__ float dot4(float4 a, float4 b) {
    return a.x*b.x + a.y*b.y + a.z*b.z + a.w*b.w;
}

// ---- kernel 1: fp32 item table -> packed int4 table in workspace ----
// 8 elems per thread: 32 B in, 4 B out.
__global__ __launch_bounds__(256) void cvt_int4_kernel(
    const float4* __restrict__ in4, unsigned* __restrict__ out, int n8)
{
    const int i = blockIdx.x * 256 + threadIdx.x;
    if (i >= n8) return;
    const float4 x0 = in4[2 * i];
    const float4 x1 = in4[2 * i + 1];
    const float v[8] = {x0.x, x0.y, x0.z, x0.w, x1.x, x1.y, x1.z, x1.w};
    unsigned p = 0;
    #pragma unroll
    for (int j = 0; j < 8; ++j) {
        int q = (int)rintf(v[j] * 64.0f);
        q = q < -8 ? -8 : (q > 7 ? 7 : q);
        p |= ((unsigned)(q & 0xF)) << (4 * j);
    }
    out[i] = p;
}

// ---- kernel 2: R9 structure, int4 table. One wave per batch element,
// 4 groups of 16 lanes; group g handles 13/13/12/12 rows; indices in lane
// registers, distributed via __shfl (no LDS, no barrier).
// x-rows: int4 (32 B/row, <=1 line). y/u rows: original fp32 (coalesced).
// out[b] = sigmoid( sum_l z_l*w_l + u_e.y_e ), z = softmax(w)  [BETA=ALPHA=1]
__global__ __launch_bounds__(256, 4) void RUM_72980084294375_kernel(
    const int* __restrict__ u, const int* __restrict__ X, const int* __restrict__ y,
    const unsigned short* __restrict__ itemq, const float* __restrict__ item_emb,
    const float* __restrict__ user_emb, float* __restrict__ out)
{
    const int tid    = threadIdx.x;
    const int wave   = tid >> 6;
    const int lane   = tid & 63;
    const int lane16 = lane & 15;
    const int g      = lane >> 4;
    const int b      = __builtin_amdgcn_readfirstlane(blockIdx.x * 4 + wave);

    // issue ALL independent loads up front: indices (lane-owned), y-row, u-row
    int xi = 0;
    if (lane < HIST) xi = X[b * HIST + lane];           // coalesced 200 B

    const float4* item4 = reinterpret_cast<const float4*>(item_emb);
    const float4* user4 = reinterpret_cast<const float4*>(user_emb);
    const int yi = y[b];                                // wave-uniform scalars
    const int ui = u[b];
    const float4 y4 = item4[(size_t)yi * 16 + lane16];  // exact fp32
    const float4 u4 = user4[(size_t)ui * 16 + lane16];  // exact fp32

    const int start = (g < 2) ? g * 13 : 26 + (g - 2) * 12;
    const int count = (g < 2) ? 13 : 12;

    // distribute indices to groups via bpermute (no LDS, no barrier)
    int idxs[13];
    #pragma unroll
    for (int k = 0; k < 13; ++k) {
        const int s = __shfl(xi, start + k, 64);
        idxs[k] = (k < count) ? s : 0;                  // row 0 = zeros
    }

    // issue all 13 row-gathers back-to-back (2 B/lane, 32 B/row, 1 line max)
    unsigned q[13];
    #pragma unroll
    for (int k = 0; k < 13; ++k)
        q[k] = itemq[(size_t)idxs[k] * 16 + lane16];

    const float uy = red16_add(dot4(u4, y4));           // overlaps gather

    // fold the 2^-6 dequant scale into y once
    const float4 ys = make_float4(y4.x * 0.015625f, y4.y * 0.015625f,
                                  y4.z * 0.015625f, y4.w * 0.015625f);

    // decode 4 nibbles (sign-extended) + dot + 16-lane reduce
    float wv = -1e30f;
    #pragma unroll
    for (int k = 0; k < 13; ++k) {
        const int qi = (int)q[k];
        const int t0 = (qi << 28) >> 28;
        const int t1 = (qi << 24) >> 28;
        const int t2 = (qi << 20) >> 28;
        const int t3 = (qi << 16) >> 28;
        const float w = red16_add((float)t0 * ys.x + (float)t1 * ys.y +
                                  (float)t2 * ys.z + (float)t3 * ys.w);
        if (k < count && lane16 == k) wv = w;
    }

    // softmax-weighted mean across all 50 (16-lane reduce + cross-group)
    float m = wv;
    #pragma unroll
    for (int d = 1; d < 16; d <<= 1) m = fmaxf(m, __shfl_xor(m, d, 16));
    m = fmaxf(m, __shfl_xor(m, 16, 64));
    m = fmaxf(m, __shfl_xor(m, 32, 64));

    const float e = __expf(wv - m);                     // pads: exp(-huge)=0
    float s = red16_add(e);
    float t = red16_add(e * wv);
    s += __shfl_xor(s, 16, 64);  s += __shfl_xor(s, 32, 64);
    t += __shfl_xor(t, 16, 64);  t += __shfl_xor(t, 32, 64);

    if (lane == 0) {
        const float logit = t / s + uy;
        out[b] = 1.0f / (1.0f + __expf(-logit));
    }
}

// ---- fp32 fallback if ws is too small (R7 structure) ----
__global__ __launch_bounds__(256, 4) void RUM_72980084294375_f32_kernel(
    const int* __restrict__ u, const int* __restrict__ X, const int* __restrict__ y,
    const float* __restrict__ item_emb, const float* __restrict__ user_emb,
    float* __restrict__ out)
{
    __shared__ int sX[4 * HIST];
    const int tid = threadIdx.x;
    const int b0  = blockIdx.x * 4;

    const int wave   = tid >> 6;
    const int lane   = tid & 63;
    const int lane16 = lane & 15;
    const int g      = lane >> 4;
    const int b      = __builtin_amdgcn_readfirstlane(b0 + wave);

    const float4* item4 = reinterpret_cast<const float4*>(item_emb);
    const float4* user4 = reinterpret_cast<const float4*>(user_emb);
    const int yi = y[b];
    const int ui = u[b];
    const float4 y4 = item4[(size_t)yi * 16 + lane16];
    const float4 u4 = user4[(size_t)ui * 16 + lane16];

    if (tid < 4 * HIST) sX[tid] = X[b0 * HIST + tid];
    __syncthreads();

    const float uy = red16_add(dot4(u4, y4));

    const int start = (g < 2) ? g * 13 : 26 + (g - 2) * 12;
    const int count = (g < 2) ? 13 : 12;
    const int* wX = sX + wave * HIST;

    float wv = -1e30f;
    #pragma unroll
    for (int k = 0; k < 13; ++k) {
        const int idx = (k < count) ? wX[start + k] : 0;
        const float4 x4 = item4[(size_t)idx * 16 + lane16];
        float wk = red16_add(dot4(x4, y4));
        if (k < count && lane16 == k) wv = wk;
    }

    float m = wv;
    #pragma unroll
    for (int d = 1; d < 16; d <<= 1) m = fmaxf(m, __shfl_xor(m, d, 16));
    m = fmaxf(m, __shfl_xor(m, 16, 64));
    m = fmaxf(m, __shfl_xor(m, 32, 64));

    const float e = __expf(wv - m);
    float s = red16_add(e);
    float t = red16_add(e * wv);
    s += __shfl_xor(s, 16, 64);  s += __shfl_xor(s, 32, 64);
    t += __shfl_xor(t, 16, 64);  t += __shfl_xor(t, 32, 64);

    if (lane == 0) {
        const float logit = t / s + uy;
        out[b] = 1.0f / (1.0f + __expf(-logit));
    }
}

extern "C" void kernel_launch(void* const* d_in, const int* in_sizes, int n_in,
                              void* d_out, int out_size, void* d_ws, size_t ws_size,
                              hipStream_t stream) {
    const int*   u        = (const int*)d_in[0];
    const int*   X        = (const int*)d_in[1];
    const int*   y        = (const int*)d_in[2];
    const float* item_emb = (const float*)d_in[3];
    const float* user_emb = (const float*)d_in[4];
    float*       out      = (float*)d_out;

    const size_t need = (size_t)ITEM_ROWS * EMB / 2;   // 3.2 MB int4 table

    if (ws_size >= need) {
        const int n8 = ITEM_ROWS * EMB / 8;            // 800008 (divides exactly)
        cvt_int4_kernel<<<(n8 + 255) / 256, 256, 0, stream>>>(
            (const float4*)item_emb, (unsigned*)d_ws, n8);
        RUM_72980084294375_kernel<<<BATCH / 4, 256, 0, stream>>>(
            u, X, y, (const unsigned short*)d_ws, item_emb, user_emb, out);
    } else {
        RUM_72980084294375_f32_kernel<<<BATCH / 4, 256, 0, stream>>>(
            u, X, y, item_emb, user_emb, out);
    }
}